// Round 1
// 477.851 us; speedup vs baseline: 1.0951x; 1.0951x over previous
//
#include <hip/hip_runtime.h>
#include <hip/hip_fp16.h>
#include <math.h>

#define IN_DIM   128
#define OUT_DIM  128
#define D_TIME   64
#define NSRC     50000
#define NDST     50000
#define NE       800000
#define NPB      20         // nodes per transform block (2500 blocks)
#define SLOTS    64         // max degree slots per dst (Poisson(16): P(>=64)~1e-19)
#define EPB      64         // edges per block in k_edge
#define INV_SCALE 0.05590169943749474f  // 1/sqrt(2*128+64)

// v_s[k] = sum_j W_src[j][k]*attn[j] ; v_d[k] = sum_j W_dst[j][k]*attn[128+j]
// One wave per output element (256 outputs, 64 blocks) instead of 1 serial block.
__global__ __launch_bounds__(256) void k_prevec(const float* __restrict__ Ws,
                                                const float* __restrict__ Wd,
                                                const float* __restrict__ attn,
                                                float* __restrict__ v_s,
                                                float* __restrict__ v_d){
    int wv = threadIdx.x >> 6, lane = threadIdx.x & 63;
    int o = blockIdx.x * 4 + wv;           // 0..255 (wave-uniform)
    const float* W = (o < 128) ? Ws : Wd;
    const float* a = (o < 128) ? attn : attn + OUT_DIM;
    float*       v = (o < 128) ? v_s : v_d;
    int k = o & 127;
    int j = 2 * lane;
    float acc = W[(size_t)j*IN_DIM + k] * a[j] + W[(size_t)(j+1)*IN_DIM + k] * a[j+1];
    #pragma unroll
    for (int off = 32; off > 0; off >>= 1) acc += __shfl_down(acc, off, 64);
    if (lane == 0) v[k] = acc;
}

// Fused front end, one grid:
//   blocks [0, 2500):            Z[node] = fp16(W_src @ h_src[node]), 2 halves x 10 nodes
//   blocks [2500, 2500+25000):   s_src / s_dst dot products + counts zeroing
__global__ __launch_bounds__(256) void k_front(const float* __restrict__ h_src,
                                               const float* __restrict__ h_dst,
                                               const float* __restrict__ W,
                                               const float* __restrict__ v_s,
                                               const float* __restrict__ v_d,
                                               __half* __restrict__ Zh,
                                               float* __restrict__ s_src,
                                               float* __restrict__ s_dst,
                                               int* __restrict__ counts){
    int t = threadIdx.x;
    if (blockIdx.x < NSRC/NPB){
        // ---- transform path: 256 threads = two independent 128-thread halves ----
        __shared__ float h[2][2][IN_DIM];          // [half][dbuf][dim]
        int hh = t >> 7, tl = t & 127;
        // W row tl (32 float4) in registers, reused across 10 nodes
        float4 wreg[32];
        const float4* wvp = (const float4*)(W + (size_t)tl * IN_DIM);
        #pragma unroll
        for (int i = 0; i < 32; ++i) wreg[i] = wvp[i];
        int base = blockIdx.x * NPB + hh * (NPB/2);
        h[hh][0][tl] = h_src[(size_t)base*IN_DIM + tl];
        for (int nn = 0; nn < NPB/2; ++nn){
            __syncthreads();
            if (nn + 1 < NPB/2) h[hh][(nn+1)&1][tl] = h_src[(size_t)(base+nn+1)*IN_DIM + tl];
            const float* hc = h[hh][nn&1];
            float acc = 0.f;
            #pragma unroll
            for (int i = 0; i < 32; ++i){
                float4 w = wreg[i]; int k = i*4;
                acc += hc[k+0]*w.x + hc[k+1]*w.y + hc[k+2]*w.z + hc[k+3]*w.w;
            }
            Zh[(size_t)(base+nn)*OUT_DIM + tl] = __float2half_rn(acc);
        }
    } else {
        // ---- dots path: 4 nodes per block, one wave each ----
        __shared__ float vd[IN_DIM];
        int b = blockIdx.x - NSRC/NPB;
        bool isDst = (b >= NSRC/4);
        const float* h = isDst ? h_dst : h_src;
        const float* v = isDst ? v_d  : v_s;
        float*       s = isDst ? s_dst : s_src;
        int bb = isDst ? (b - NSRC/4) : b;
        if (t < IN_DIM) vd[t] = v[t];
        __syncthreads();
        int wave = t >> 6, lane = t & 63;
        int node = bb * 4 + wave;
        float2 u = ((const float2*)(h + (size_t)node*IN_DIM))[lane];
        float acc = u.x*vd[2*lane] + u.y*vd[2*lane+1];
        #pragma unroll
        for (int off = 32; off > 0; off >>= 1) acc += __shfl_down(acc, off, 64);
        if (lane == 0){
            s[node] = acc;
            if (isDst) counts[node] = 0;   // replaces hipMemsetAsync
        }
    }
}

// Fused score + slot: phi . a_t (16 lanes/edge, streaming) -> LDS -> per-edge
// compose + leaky + bucket. Kills the pt global round-trip.
__global__ __launch_bounds__(256) void k_edge(const float* __restrict__ phi,
                                              const float* __restrict__ attn,
                                              const int* __restrict__ ei,
                                              const float* __restrict__ s_src,
                                              const float* __restrict__ s_dst,
                                              int2* __restrict__ slots,
                                              int* __restrict__ counts){
    __shared__ float at[D_TIME];
    __shared__ float pts[EPB];
    int t = threadIdx.x;
    if (t < D_TIME) at[t] = attn[2*OUT_DIM + t];
    __syncthreads();
    int sub = t & 15, g = t >> 4;
    int e0 = blockIdx.x * EPB + g;
    float a0 = at[sub*4+0], a1 = at[sub*4+1], a2 = at[sub*4+2], a3 = at[sub*4+3];
    float4 w[4];
    #pragma unroll
    for (int p = 0; p < 4; ++p)
        w[p] = ((const float4*)(phi + (size_t)(e0 + p*16) * D_TIME))[sub];
    #pragma unroll
    for (int p = 0; p < 4; ++p){
        float acc = w[p].x*a0 + w[p].y*a1 + w[p].z*a2 + w[p].w*a3;
        #pragma unroll
        for (int off = 8; off > 0; off >>= 1) acc += __shfl_xor(acc, off, 64);
        if (sub == 0) pts[g + p*16] = acc;
    }
    __syncthreads();
    if (t < EPB){
        int e = blockIdx.x * EPB + t;
        int src = ei[e], dst = ei[NE + e];
        float v = s_src[src] + s_dst[dst] + pts[t];
        v = (v > 0.f) ? v : 0.2f * v;
        v *= INV_SCALE;
        int k = atomicAdd(&counts[dst], 1);
        if (k < SLOTS) slots[(dst << 6) + k] = make_int2(src, __float_as_int(v));
    }
}

// per-dst softmax + weighted fp16-Z accumulation. One wave per dst, 4 dst/block.
// Lanes >= cnt carry alpha == 0 exactly, so the x4-unrolled loop over-iterates safely.
__global__ __launch_bounds__(256) void k_agg(const int* __restrict__ counts,
                                             const int2* __restrict__ slots,
                                             const __half* __restrict__ Zh,
                                             float* __restrict__ out){
    int wv = threadIdx.x >> 6, lane = threadIdx.x & 63;
    int d = blockIdx.x * 4 + wv;
    int cnt = counts[d]; cnt = (cnt > SLOTS) ? SLOTS : cnt;
    float e = -1e30f; int src = 0;
    if (lane < cnt){
        int2 s = slots[(d << 6) + lane];
        src = s.x; e = __int_as_float(s.y);
    }
    float m = e;
    #pragma unroll
    for (int off = 32; off > 0; off >>= 1) m = fmaxf(m, __shfl_xor(m, off, 64));
    float ex = (lane < cnt) ? __expf(e - m) : 0.f;
    float sum = ex;
    #pragma unroll
    for (int off = 32; off > 0; off >>= 1) sum += __shfl_xor(sum, off, 64);
    float alpha = ex / (sum + 1e-12f);
    float2 acc = make_float2(0.f, 0.f);
    int jmax = (cnt + 3) & ~3;
    for (int j = 0; j < jmax; j += 4){
        float a0 = __shfl(alpha, j,   64); int s0 = __shfl(src, j,   64);
        float a1 = __shfl(alpha, j+1, 64); int s1 = __shfl(src, j+1, 64);
        float a2 = __shfl(alpha, j+2, 64); int s2 = __shfl(src, j+2, 64);
        float a3 = __shfl(alpha, j+3, 64); int s3 = __shfl(src, j+3, 64);
        __half2 z0 = ((const __half2*)(Zh + (size_t)s0 * OUT_DIM))[lane];
        __half2 z1 = ((const __half2*)(Zh + (size_t)s1 * OUT_DIM))[lane];
        __half2 z2 = ((const __half2*)(Zh + (size_t)s2 * OUT_DIM))[lane];
        __half2 z3 = ((const __half2*)(Zh + (size_t)s3 * OUT_DIM))[lane];
        float2 f0 = __half22float2(z0);
        float2 f1 = __half22float2(z1);
        float2 f2 = __half22float2(z2);
        float2 f3 = __half22float2(z3);
        acc.x += a0*f0.x + a1*f1.x + a2*f2.x + a3*f3.x;
        acc.y += a0*f0.y + a1*f1.y + a2*f2.y + a3*f3.y;
    }
    ((float2*)(out + (size_t)d * OUT_DIM))[lane] = acc;
}

extern "C" void kernel_launch(void* const* d_in, const int* in_sizes, int n_in,
                              void* d_out, int out_size, void* d_ws, size_t ws_size,
                              hipStream_t stream){
    const float* h_src = (const float*)d_in[0];
    const float* h_dst = (const float*)d_in[1];
    const int*   ei    = (const int*)d_in[2];
    const float* phi   = (const float*)d_in[3];
    const float* Wsrc  = (const float*)d_in[4];
    const float* Wdst  = (const float*)d_in[5];
    const float* attn  = (const float*)d_in[6];
    float* out = (float*)d_out;

    char* p = (char*)d_ws;
    auto alloc = [&](size_t bytes)->char*{
        char* r = p; p += (bytes + 255) / 256 * 256; return r;
    };
    __half* Zh   = (__half*)alloc((size_t)NSRC*OUT_DIM*2);
    float* s_src = (float*)alloc((size_t)NSRC*4);
    float* s_dst = (float*)alloc((size_t)NDST*4);
    float* v_s   = (float*)alloc(128*4);
    float* v_d   = (float*)alloc(128*4);
    int2*  slots = (int2*)alloc((size_t)NDST*SLOTS*8);
    int*   counts= (int*)alloc((size_t)NDST*4);

    k_prevec<<<64, 256, 0, stream>>>(Wsrc, Wdst, attn, v_s, v_d);
    k_front<<<NSRC/NPB + (NSRC + NDST)/4, 256, 0, stream>>>(
        h_src, h_dst, Wsrc, v_s, v_d, Zh, s_src, s_dst, counts);
    k_edge<<<NE/EPB, 256, 0, stream>>>(phi, attn, ei, s_src, s_dst, slots, counts);
    k_agg<<<NDST/4, 256, 0, stream>>>(counts, slots, Zh, out);
}

// Round 2
// 463.284 us; speedup vs baseline: 1.1296x; 1.0314x over previous
//
#include <hip/hip_runtime.h>
#include <hip/hip_fp16.h>
#include <math.h>

#define IN_DIM   128
#define OUT_DIM  128
#define D_TIME   64
#define NSRC     50000
#define NDST     50000
#define NE       800000
#define NPB      20         // nodes per transform block (2500 blocks)
#define SLOTS    64         // max degree slots per dst (Poisson(16): P(>=64)~1e-19)
#define EPB      256        // edges per block in k_edge
#define INV_SCALE 0.05590169943749474f  // 1/sqrt(2*128+64)

// v_s[k] = sum_j W_src[j][k]*attn[j] ; v_d[k] = sum_j W_dst[j][k]*attn[128+j]
__global__ __launch_bounds__(256) void k_prevec(const float* __restrict__ Ws,
                                                const float* __restrict__ Wd,
                                                const float* __restrict__ attn,
                                                float* __restrict__ v_s,
                                                float* __restrict__ v_d){
    int wv = threadIdx.x >> 6, lane = threadIdx.x & 63;
    int o = blockIdx.x * 4 + wv;           // 0..255 (wave-uniform)
    const float* W = (o < 128) ? Ws : Wd;
    const float* a = (o < 128) ? attn : attn + OUT_DIM;
    float*       v = (o < 128) ? v_s : v_d;
    int k = o & 127;
    int j = 2 * lane;
    float acc = W[(size_t)j*IN_DIM + k] * a[j] + W[(size_t)(j+1)*IN_DIM + k] * a[j+1];
    #pragma unroll
    for (int off = 32; off > 0; off >>= 1) acc += __shfl_down(acc, off, 64);
    if (lane == 0) v[k] = acc;
}

// Fused front end, one grid:
//   blocks [0, 2500):            Zh[node] = fp16(W_src @ h_src[node])
//     Split-K: thread t owns row r=t>>1, K-half kh=t&1 -> 16 float4 of W (64 VGPR,
//     fits the 128-VGPR budget of __launch_bounds__(256,4); the previous 32-float4
//     version spilled at VGPR_Count=80 and cost ~3.3 GB of W re-reads).
//   blocks [2500, 2500+25000):   s_src / s_dst dot products + counts zeroing
__global__ __launch_bounds__(256, 4) void k_front(const float* __restrict__ h_src,
                                                  const float* __restrict__ h_dst,
                                                  const float* __restrict__ W,
                                                  const float* __restrict__ v_s,
                                                  const float* __restrict__ v_d,
                                                  __half* __restrict__ Zh,
                                                  float* __restrict__ s_src,
                                                  float* __restrict__ s_dst,
                                                  int* __restrict__ counts){
    int t = threadIdx.x;
    if (blockIdx.x < NSRC/NPB){
        // ---- transform path: all 256 threads on one node, 20 nodes/block ----
        __shared__ float hbuf[2][IN_DIM];
        int r  = t >> 1;      // output row 0..127
        int kh = t & 1;       // K half
        float4 wreg[16];
        const float4* wvp = (const float4*)(W + (size_t)r * IN_DIM + kh * 64);
        #pragma unroll
        for (int i = 0; i < 16; ++i) wreg[i] = wvp[i];
        int base = blockIdx.x * NPB;
        if (t < IN_DIM) hbuf[0][t] = h_src[(size_t)base*IN_DIM + t];
        for (int nn = 0; nn < NPB; ++nn){
            __syncthreads();
            if (nn + 1 < NPB && t < IN_DIM)
                hbuf[(nn+1)&1][t] = h_src[(size_t)(base+nn+1)*IN_DIM + t];
            const float* hc = hbuf[nn&1] + kh*64;
            float acc = 0.f;
            #pragma unroll
            for (int i = 0; i < 16; ++i){
                float4 w = wreg[i]; int k = i*4;
                acc += hc[k+0]*w.x + hc[k+1]*w.y + hc[k+2]*w.z + hc[k+3]*w.w;
            }
            acc += __shfl_xor(acc, 1, 64);   // combine K halves (lanes t, t^1)
            if (!kh) Zh[(size_t)(base+nn)*OUT_DIM + r] = __float2half_rn(acc);
        }
    } else {
        // ---- dots path: 4 nodes per block, one wave each ----
        __shared__ float vd[IN_DIM];
        int b = blockIdx.x - NSRC/NPB;
        bool isDst = (b >= NSRC/4);
        const float* h = isDst ? h_dst : h_src;
        const float* v = isDst ? v_d  : v_s;
        float*       s = isDst ? s_dst : s_src;
        int bb = isDst ? (b - NSRC/4) : b;
        if (t < IN_DIM) vd[t] = v[t];
        __syncthreads();
        int wave = t >> 6, lane = t & 63;
        int node = bb * 4 + wave;
        float2 u = ((const float2*)(h + (size_t)node*IN_DIM))[lane];
        float acc = u.x*vd[2*lane] + u.y*vd[2*lane+1];
        #pragma unroll
        for (int off = 32; off > 0; off >>= 1) acc += __shfl_down(acc, off, 64);
        if (lane == 0){
            s[node] = acc;
            if (isDst) counts[node] = 0;   // replaces hipMemsetAsync
        }
    }
}

// Fused score + slot, 256 edges/block: phi . a_t (16 lanes/edge, 4-deep float4
// prefetch) -> LDS -> per-edge compose + leaky + bucket.
__global__ __launch_bounds__(256) void k_edge(const float* __restrict__ phi,
                                              const float* __restrict__ attn,
                                              const int* __restrict__ ei,
                                              const float* __restrict__ s_src,
                                              const float* __restrict__ s_dst,
                                              int2* __restrict__ slots,
                                              int* __restrict__ counts){
    __shared__ float at[D_TIME];
    __shared__ float pts[EPB];
    int t = threadIdx.x;
    if (t < D_TIME) at[t] = attn[2*OUT_DIM + t];
    __syncthreads();
    int sub = t & 15, g = t >> 4;           // 16 groups of 16 lanes
    int e0 = blockIdx.x * EPB + g;
    float a0 = at[sub*4+0], a1 = at[sub*4+1], a2 = at[sub*4+2], a3 = at[sub*4+3];
    #pragma unroll
    for (int pp = 0; pp < 16; pp += 4){
        float4 w[4];
        #pragma unroll
        for (int q = 0; q < 4; ++q)
            w[q] = ((const float4*)(phi + (size_t)(e0 + (pp+q)*16) * D_TIME))[sub];
        #pragma unroll
        for (int q = 0; q < 4; ++q){
            float acc = w[q].x*a0 + w[q].y*a1 + w[q].z*a2 + w[q].w*a3;
            #pragma unroll
            for (int off = 8; off > 0; off >>= 1) acc += __shfl_xor(acc, off, 64);
            if (sub == 0) pts[g + (pp+q)*16] = acc;
        }
    }
    __syncthreads();
    int e = blockIdx.x * EPB + t;
    int src = ei[e], dst = ei[NE + e];
    float v = s_src[src] + s_dst[dst] + pts[t];
    v = (v > 0.f) ? v : 0.2f * v;
    v *= INV_SCALE;
    int k = atomicAdd(&counts[dst], 1);
    if (k < SLOTS) slots[(dst << 6) + k] = make_int2(src, __float_as_int(v));
}

// per-dst softmax + weighted fp16-Z accumulation. One wave per dst, 4 dst/block.
// Lanes >= cnt carry alpha == 0 exactly, so the x8-unrolled loop over-iterates safely.
__global__ __launch_bounds__(256) void k_agg(const int* __restrict__ counts,
                                             const int2* __restrict__ slots,
                                             const __half* __restrict__ Zh,
                                             float* __restrict__ out){
    int wv = threadIdx.x >> 6, lane = threadIdx.x & 63;
    int d = blockIdx.x * 4 + wv;
    int cnt = counts[d]; cnt = (cnt > SLOTS) ? SLOTS : cnt;
    float e = -1e30f; int src = 0;
    if (lane < cnt){
        int2 s = slots[(d << 6) + lane];
        src = s.x; e = __int_as_float(s.y);
    }
    float m = e;
    #pragma unroll
    for (int off = 32; off > 0; off >>= 1) m = fmaxf(m, __shfl_xor(m, off, 64));
    float ex = (lane < cnt) ? __expf(e - m) : 0.f;
    float sum = ex;
    #pragma unroll
    for (int off = 32; off > 0; off >>= 1) sum += __shfl_xor(sum, off, 64);
    float alpha = ex / (sum + 1e-12f);
    float2 acc = make_float2(0.f, 0.f);
    int jmax = (cnt + 7) & ~7;
    for (int j = 0; j < jmax; j += 8){
        float a[8]; int s[8];
        #pragma unroll
        for (int q = 0; q < 8; ++q){
            a[q] = __shfl(alpha, j+q, 64);
            s[q] = __shfl(src,   j+q, 64);
        }
        __half2 z[8];
        #pragma unroll
        for (int q = 0; q < 8; ++q)
            z[q] = ((const __half2*)(Zh + (size_t)s[q] * OUT_DIM))[lane];
        #pragma unroll
        for (int q = 0; q < 8; ++q){
            float2 f = __half22float2(z[q]);
            acc.x += a[q]*f.x;
            acc.y += a[q]*f.y;
        }
    }
    ((float2*)(out + (size_t)d * OUT_DIM))[lane] = acc;
}

extern "C" void kernel_launch(void* const* d_in, const int* in_sizes, int n_in,
                              void* d_out, int out_size, void* d_ws, size_t ws_size,
                              hipStream_t stream){
    const float* h_src = (const float*)d_in[0];
    const float* h_dst = (const float*)d_in[1];
    const int*   ei    = (const int*)d_in[2];
    const float* phi   = (const float*)d_in[3];
    const float* Wsrc  = (const float*)d_in[4];
    const float* Wdst  = (const float*)d_in[5];
    const float* attn  = (const float*)d_in[6];
    float* out = (float*)d_out;

    char* p = (char*)d_ws;
    auto alloc = [&](size_t bytes)->char*{
        char* r = p; p += (bytes + 255) / 256 * 256; return r;
    };
    __half* Zh   = (__half*)alloc((size_t)NSRC*OUT_DIM*2);
    float* s_src = (float*)alloc((size_t)NSRC*4);
    float* s_dst = (float*)alloc((size_t)NDST*4);
    float* v_s   = (float*)alloc(128*4);
    float* v_d   = (float*)alloc(128*4);
    int2*  slots = (int2*)alloc((size_t)NDST*SLOTS*8);
    int*   counts= (int*)alloc((size_t)NDST*4);

    k_prevec<<<64, 256, 0, stream>>>(Wsrc, Wdst, attn, v_s, v_d);
    k_front<<<NSRC/NPB + (NSRC + NDST)/4, 256, 0, stream>>>(
        h_src, h_dst, Wsrc, v_s, v_d, Zh, s_src, s_dst, counts);
    k_edge<<<NE/EPB, 256, 0, stream>>>(phi, attn, ei, s_src, s_dst, slots, counts);
    k_agg<<<NDST/4, 256, 0, stream>>>(counts, slots, Zh, out);
}

// Round 3
// 449.720 us; speedup vs baseline: 1.1636x; 1.0302x over previous
//
#include <hip/hip_runtime.h>
#include <hip/hip_fp16.h>
#include <math.h>

#define IN_DIM   128
#define OUT_DIM  128
#define D_TIME   64
#define NSRC     50000
#define NDST     50000
#define NE       800000
#define NPB      40         // nodes per transform block (1250 blocks)
#define GR       4          // nodes per sync round
#define NR       (NPB/GR)   // 10 rounds
#define DPB      16         // dst nodes per dots block (3125 blocks)
#define SLOTS    64         // max degree slots per dst (Poisson(16): P(>=64)~1e-19)
#define EPB      256        // edges per block in k_edge
#define INV_SCALE 0.05590169943749474f  // 1/sqrt(2*128+64)

// v_d[k] = sum_j W_dst[j][k]*attn[128+j]   (v_s no longer needed: s_src is
// computed inside the transform from the fp32 Z registers)
__global__ __launch_bounds__(256) void k_prevec(const float* __restrict__ Wd,
                                                const float* __restrict__ attn,
                                                float* __restrict__ v_d){
    int wv = threadIdx.x >> 6, lane = threadIdx.x & 63;
    int k = blockIdx.x * 4 + wv;           // 0..127
    int j = 2 * lane;
    float acc = Wd[(size_t)j*IN_DIM + k] * attn[OUT_DIM + j]
              + Wd[(size_t)(j+1)*IN_DIM + k] * attn[OUT_DIM + j + 1];
    #pragma unroll
    for (int off = 32; off > 0; off >>= 1) acc += __shfl_down(acc, off, 64);
    if (lane == 0) v_d[k] = acc;
}

// Fused front end, one grid:
//   blocks [0, 1250):   Zh[node]=fp16(W@h_src[node]) AND s_src[node]=Z.a_s
//     4 nodes per sync round (2KB staged, 10 syncs/block), split-K W in regs.
//   blocks [1250, 1250+3125): s_dst dots (16 nodes/block) + counts zeroing
__global__ __launch_bounds__(256, 4) void k_front(const float* __restrict__ h_src,
                                                  const float* __restrict__ h_dst,
                                                  const float* __restrict__ W,
                                                  const float* __restrict__ attn,
                                                  const float* __restrict__ v_d,
                                                  __half* __restrict__ Zh,
                                                  float* __restrict__ s_src,
                                                  float* __restrict__ s_dst,
                                                  int* __restrict__ counts){
    int t = threadIdx.x;
    if (blockIdx.x < NSRC/NPB){
        // ---- transform path ----
        __shared__ float hbuf[2][GR][IN_DIM];
        __shared__ float sred[2][4][GR];
        int r  = t >> 1;      // output row 0..127
        int kh = t & 1;       // K half
        int wv = t >> 6, lane = t & 63;
        float a_r = attn[r];  // a_s[r]
        float4 wreg[16];
        const float4* wvp = (const float4*)(W + (size_t)r * IN_DIM + kh * 64);
        #pragma unroll
        for (int i = 0; i < 16; ++i) wreg[i] = wvp[i];
        int base = blockIdx.x * NPB;
        // loader: wave wv loads node (round*GR + wv), 8B/lane coalesced
        ((float2*)hbuf[0][wv])[lane] =
            ((const float2*)(h_src + (size_t)(base + wv)*IN_DIM))[lane];
        for (int rnd = 0; rnd < NR; ++rnd){
            __syncthreads();
            if (rnd + 1 < NR)
                ((float2*)hbuf[(rnd+1)&1][wv])[lane] =
                    ((const float2*)(h_src + (size_t)(base + (rnd+1)*GR + wv)*IN_DIM))[lane];
            if (rnd > 0 && t < GR){
                int pb = (rnd-1)&1;
                s_src[base + (rnd-1)*GR + t] =
                    0.5f*(sred[pb][0][t]+sred[pb][1][t]+sred[pb][2][t]+sred[pb][3][t]);
            }
            #pragma unroll
            for (int g = 0; g < GR; ++g){
                const float* hc = hbuf[rnd&1][g] + kh*64;
                float acc = 0.f;
                #pragma unroll
                for (int i = 0; i < 16; ++i){
                    float4 w = wreg[i]; int k = i*4;
                    acc += hc[k+0]*w.x + hc[k+1]*w.y + hc[k+2]*w.z + hc[k+3]*w.w;
                }
                acc += __shfl_xor(acc, 1, 64);   // combine K halves
                if (!kh) Zh[(size_t)(base+rnd*GR+g)*OUT_DIM + r] = __float2half_rn(acc);
                // s_src contribution: both kh lanes hold Z[r] -> 0.5 factor later
                float c = acc * a_r;
                #pragma unroll
                for (int off = 32; off > 0; off >>= 1) c += __shfl_xor(c, off, 64);
                if (lane == 0) sred[rnd&1][wv][g] = c;
            }
        }
        __syncthreads();
        if (t < GR){
            int pb = (NR-1)&1;
            s_src[base + (NR-1)*GR + t] =
                0.5f*(sred[pb][0][t]+sred[pb][1][t]+sred[pb][2][t]+sred[pb][3][t]);
        }
    } else {
        // ---- dst dots: 16 nodes/block, 4 waves x 4 sequential nodes ----
        __shared__ float vd[IN_DIM];
        int b = blockIdx.x - NSRC/NPB;   // 0..3124
        if (t < IN_DIM) vd[t] = v_d[t];
        __syncthreads();
        int wv = t >> 6, lane = t & 63;
        float v0 = vd[2*lane], v1 = vd[2*lane+1];
        int n0 = b * DPB + wv;
        float2 u[4];
        #pragma unroll
        for (int it = 0; it < 4; ++it)
            u[it] = ((const float2*)(h_dst + (size_t)(n0 + it*4)*IN_DIM))[lane];
        #pragma unroll
        for (int it = 0; it < 4; ++it){
            float acc = u[it].x*v0 + u[it].y*v1;
            #pragma unroll
            for (int off = 32; off > 0; off >>= 1) acc += __shfl_down(acc, off, 64);
            if (lane == 0){
                s_dst[n0 + it*4] = acc;
                counts[n0 + it*4] = 0;   // replaces hipMemsetAsync
            }
        }
    }
}

// Fused score + slot, 256 edges/block: phi . a_t (16 lanes/edge, 8-deep float4
// prefetch) -> LDS -> per-edge compose + leaky + bucket.
__global__ __launch_bounds__(256) void k_edge(const float* __restrict__ phi,
                                              const float* __restrict__ attn,
                                              const int* __restrict__ ei,
                                              const float* __restrict__ s_src,
                                              const float* __restrict__ s_dst,
                                              int2* __restrict__ slots,
                                              int* __restrict__ counts){
    __shared__ float at[D_TIME];
    __shared__ float pts[EPB];
    int t = threadIdx.x;
    if (t < D_TIME) at[t] = attn[2*OUT_DIM + t];
    __syncthreads();
    int sub = t & 15, g = t >> 4;           // 16 groups of 16 lanes
    int e0 = blockIdx.x * EPB + g;
    float a0 = at[sub*4+0], a1 = at[sub*4+1], a2 = at[sub*4+2], a3 = at[sub*4+3];
    #pragma unroll
    for (int pp = 0; pp < 16; pp += 8){
        float4 w[8];
        #pragma unroll
        for (int q = 0; q < 8; ++q)
            w[q] = ((const float4*)(phi + (size_t)(e0 + (pp+q)*16) * D_TIME))[sub];
        #pragma unroll
        for (int q = 0; q < 8; ++q){
            float acc = w[q].x*a0 + w[q].y*a1 + w[q].z*a2 + w[q].w*a3;
            #pragma unroll
            for (int off = 8; off > 0; off >>= 1) acc += __shfl_xor(acc, off, 64);
            if (sub == 0) pts[g + (pp+q)*16] = acc;
        }
    }
    __syncthreads();
    int e = blockIdx.x * EPB + t;
    int src = ei[e], dst = ei[NE + e];
    float v = s_src[src] + s_dst[dst] + pts[t];
    v = (v > 0.f) ? v : 0.2f * v;
    v *= INV_SCALE;
    int k = atomicAdd(&counts[dst], 1);
    if (k < SLOTS) slots[(dst << 6) + k] = make_int2(src, __float_as_int(v));
}

// per-dst softmax + weighted fp16-Z accumulation. One wave per dst, 4 dst/block.
// Gather: half-wave per row (32 lanes x 8B = one 256B row), so one wave pulls
// 2 rows per load instr; 8 slots in flight; shfl_xor(32) combine; float4 store.
__global__ __launch_bounds__(256) void k_agg(const int* __restrict__ counts,
                                             const int2* __restrict__ slots,
                                             const __half* __restrict__ Zh,
                                             float* __restrict__ out){
    int wv = threadIdx.x >> 6, lane = threadIdx.x & 63;
    int half = lane >> 5, sl = lane & 31;
    int d = blockIdx.x * 4 + wv;
    int cnt = counts[d]; cnt = (cnt > SLOTS) ? SLOTS : cnt;
    float e = -1e30f; int src = 0;
    if (lane < cnt){
        int2 s = slots[(d << 6) + lane];
        src = s.x; e = __int_as_float(s.y);
    }
    float m = e;
    #pragma unroll
    for (int off = 32; off > 0; off >>= 1) m = fmaxf(m, __shfl_xor(m, off, 64));
    float ex = (lane < cnt) ? __expf(e - m) : 0.f;
    float sum = ex;
    #pragma unroll
    for (int off = 32; off > 0; off >>= 1) sum += __shfl_xor(sum, off, 64);
    float alpha = ex / (sum + 1e-12f);   // lanes >= cnt: exactly 0
    float4 acc4 = make_float4(0.f, 0.f, 0.f, 0.f);
    int jmax = (cnt + 7) & ~7;
    for (int j = 0; j < jmax; j += 8){
        float a[4]; int s[4];
        #pragma unroll
        for (int q = 0; q < 4; ++q){
            int idx = j + 2*q + half;
            a[q] = __shfl(alpha, idx, 64);
            s[q] = __shfl(src,   idx, 64);
        }
        float2 raw[4];
        #pragma unroll
        for (int q = 0; q < 4; ++q)
            raw[q] = ((const float2*)(Zh + (size_t)s[q] * OUT_DIM))[sl];
        #pragma unroll
        for (int q = 0; q < 4; ++q){
            __half2 h0 = *(__half2*)&raw[q].x;
            __half2 h1 = *(__half2*)&raw[q].y;
            float2 f0 = __half22float2(h0);
            float2 f1 = __half22float2(h1);
            acc4.x += a[q]*f0.x; acc4.y += a[q]*f0.y;
            acc4.z += a[q]*f1.x; acc4.w += a[q]*f1.y;
        }
    }
    acc4.x += __shfl_xor(acc4.x, 32, 64);
    acc4.y += __shfl_xor(acc4.y, 32, 64);
    acc4.z += __shfl_xor(acc4.z, 32, 64);
    acc4.w += __shfl_xor(acc4.w, 32, 64);
    if (!half) ((float4*)(out + (size_t)d * OUT_DIM))[sl] = acc4;
}

extern "C" void kernel_launch(void* const* d_in, const int* in_sizes, int n_in,
                              void* d_out, int out_size, void* d_ws, size_t ws_size,
                              hipStream_t stream){
    const float* h_src = (const float*)d_in[0];
    const float* h_dst = (const float*)d_in[1];
    const int*   ei    = (const int*)d_in[2];
    const float* phi   = (const float*)d_in[3];
    const float* Wsrc  = (const float*)d_in[4];
    const float* Wdst  = (const float*)d_in[5];
    const float* attn  = (const float*)d_in[6];
    float* out = (float*)d_out;

    char* p = (char*)d_ws;
    auto alloc = [&](size_t bytes)->char*{
        char* r = p; p += (bytes + 255) / 256 * 256; return r;
    };
    __half* Zh   = (__half*)alloc((size_t)NSRC*OUT_DIM*2);
    float* s_src = (float*)alloc((size_t)NSRC*4);
    float* s_dst = (float*)alloc((size_t)NDST*4);
    float* v_d   = (float*)alloc(128*4);
    int2*  slots = (int2*)alloc((size_t)NDST*SLOTS*8);
    int*   counts= (int*)alloc((size_t)NDST*4);

    k_prevec<<<32, 256, 0, stream>>>(Wdst, attn, v_d);
    k_front<<<NSRC/NPB + NDST/DPB, 256, 0, stream>>>(
        h_src, h_dst, Wsrc, attn, v_d, Zh, s_src, s_dst, counts);
    k_edge<<<NE/EPB, 256, 0, stream>>>(phi, attn, ei, s_src, s_dst, slots, counts);
    k_agg<<<NDST/4, 256, 0, stream>>>(counts, slots, Zh, out);
}